// Round 6
// baseline (1066.263 us; speedup 1.0000x reference)
//
#include <hip/hip_runtime.h>

#define LEAK 0.1f
#define BN_EPS 1e-5f

constexpr int N_NODES = 100000;
constexpr int N_EDGES = 2000000;
constexpr int N_NF = 16;
constexpr int N_EF = 19;
constexpr int D0 = 2 * N_NF + N_EF;  // 51
constexpr int D1 = 64, D2 = 64, D3 = 32, D4 = 16, D5 = 8, D6 = 2;

// ws layout (in floats)
constexpr int OFF_E_SUM = 0;    // 19
constexpr int OFF_E_SQ  = 32;   // 19
constexpr int OFF_X_SUM = 64;   // 16
constexpr int OFF_X_SQ  = 96;   // 16
constexpr int OFF_W1P   = 256;            // 51*64 folded W1
constexpr int OFF_B1P   = OFF_W1P + D0 * D1;  // 64 folded b1

// ---------------- column stats (sum, sumsq) ----------------
template <int NF>
__global__ void col_stats_kernel(const float* __restrict__ v, int nrows,
                                 float* __restrict__ acc_sum,
                                 float* __restrict__ acc_sq) {
  float s[NF], q[NF];
#pragma unroll
  for (int k = 0; k < NF; k++) { s[k] = 0.f; q[k] = 0.f; }
  int tid = blockIdx.x * blockDim.x + threadIdx.x;
  int stride = gridDim.x * blockDim.x;
  for (int r = tid; r < nrows; r += stride) {
    const float* __restrict__ row = v + (size_t)r * NF;
#pragma unroll
    for (int k = 0; k < NF; k++) { float t = row[k]; s[k] += t; q[k] += t * t; }
  }
  // wave (64-lane) butterfly reduce
#pragma unroll
  for (int k = 0; k < NF; k++) {
#pragma unroll
    for (int off = 32; off > 0; off >>= 1) {
      s[k] += __shfl_down(s[k], off);
      q[k] += __shfl_down(q[k], off);
    }
  }
  __shared__ float ls[4][2 * NF];
  int wave = threadIdx.x >> 6;
  int lane = threadIdx.x & 63;
  if (lane == 0) {
#pragma unroll
    for (int k = 0; k < NF; k++) { ls[wave][k] = s[k]; ls[wave][NF + k] = q[k]; }
  }
  __syncthreads();
  if (threadIdx.x < 2 * NF) {
    float t = ls[0][threadIdx.x] + ls[1][threadIdx.x] + ls[2][threadIdx.x] +
              ls[3][threadIdx.x];
    if (threadIdx.x < NF) atomicAdd(&acc_sum[threadIdx.x], t);
    else                  atomicAdd(&acc_sq[threadIdx.x - NF], t);
  }
}

// ---------------- fold BN into W1/b1 ----------------
// scale_i = g_i / sqrt(var_i + eps); shift_i = b_i - mean_i*scale_i
// W1'[i,:] = scale_i * W1[i,:];  b1' = b1 + sum_i shift_i * W1[i,:]
__global__ void fold_bn_kernel(const float* __restrict__ ws,
                               const float* __restrict__ ng, const float* __restrict__ nb,
                               const float* __restrict__ eg, const float* __restrict__ eb,
                               const float* __restrict__ W1, const float* __restrict__ b1,
                               float* __restrict__ W1p, float* __restrict__ b1p) {
  __shared__ float sc[D0], sh[D0];
  int t = threadIdx.x;  // 64 threads
  if (t < D0) {
    float mean, var, g, b;
    if (t < 2 * N_NF) {
      int k = t & (N_NF - 1);
      mean = ws[OFF_X_SUM + k] / (float)N_NODES;
      var  = ws[OFF_X_SQ + k] / (float)N_NODES - mean * mean;
      g = ng[k]; b = nb[k];
    } else {
      int k = t - 2 * N_NF;
      mean = ws[OFF_E_SUM + k] / (float)N_EDGES;
      var  = ws[OFF_E_SQ + k] / (float)N_EDGES - mean * mean;
      g = eg[k]; b = eb[k];
    }
    float scale = g / sqrtf(var + BN_EPS);
    sc[t] = scale;
    sh[t] = b - mean * scale;
  }
  __syncthreads();
  if (t < D1) {
    float accb = b1[t];
    for (int i = 0; i < D0; i++) {
      float w = W1[i * D1 + t];
      W1p[i * D1 + t] = w * sc[i];
      accb += sh[i] * w;
    }
    b1p[t] = accb;
  }
}

// ---------------- per-edge MLP ----------------
template <int IN, int OUT, bool ACT, int NA, int NB>
__device__ __forceinline__ void layer(const float* __restrict__ W,
                                      const float* __restrict__ b,
                                      const float (&hin)[NA], float (&hout)[NB]) {
#pragma unroll
  for (int j = 0; j < OUT; j++) hout[j] = b[j];
#pragma unroll
  for (int i = 0; i < IN; i++) {
    const float a = hin[i];
#pragma unroll
    for (int j = 0; j < OUT; j++) hout[j] = fmaf(a, W[i * OUT + j], hout[j]);
  }
  if (ACT) {
#pragma unroll
    for (int j = 0; j < OUT; j++) hout[j] = hout[j] >= 0.f ? hout[j] : LEAK * hout[j];
  }
}

__device__ __forceinline__ void cpy(float* dst, const float* src, int n, int t, int nt) {
  for (int i = t; i < n; i += nt) dst[i] = src[i];
}

__global__ __launch_bounds__(256) void edge_mlp_kernel(
    const float* __restrict__ x, const float* __restrict__ e,
    const int* __restrict__ ei,
    const float* __restrict__ W1p, const float* __restrict__ b1p,
    const float* __restrict__ W2, const float* __restrict__ b2,
    const float* __restrict__ W3, const float* __restrict__ b3,
    const float* __restrict__ W4, const float* __restrict__ b4,
    const float* __restrict__ W5, const float* __restrict__ b5,
    const float* __restrict__ W6, const float* __restrict__ b6,
    float* __restrict__ out) {
  __shared__ float sW1[D0 * D1], sB1[D1];
  __shared__ float sW2[D1 * D2], sB2[D2];
  __shared__ float sW3[D2 * D3], sB3[D3];
  __shared__ float sW4[D3 * D4], sB4[D4];
  __shared__ float sW5[D4 * D5], sB5[D5];
  __shared__ float sW6[D5 * D6], sB6[D6];

  const int t = threadIdx.x, nt = blockDim.x;
  cpy(sW1, W1p, D0 * D1, t, nt); cpy(sB1, b1p, D1, t, nt);
  cpy(sW2, W2, D1 * D2, t, nt);  cpy(sB2, b2, D2, t, nt);
  cpy(sW3, W3, D2 * D3, t, nt);  cpy(sB3, b3, D3, t, nt);
  cpy(sW4, W4, D3 * D4, t, nt);  cpy(sB4, b4, D4, t, nt);
  cpy(sW5, W5, D4 * D5, t, nt);  cpy(sB5, b5, D5, t, nt);
  cpy(sW6, W6, D5 * D6, t, nt);  cpy(sB6, b6, D6, t, nt);
  __syncthreads();

  const int eidx = blockIdx.x * blockDim.x + threadIdx.x;
  if (eidx >= N_EDGES) return;

  float A[64], B[64];
  // gather src/dst node rows (64B each, float4-vectorized; x is L2-resident)
  {
    const int s = ei[eidx];
    const int d = ei[N_EDGES + eidx];
    const float4* xs = (const float4*)(x + (size_t)s * N_NF);
    const float4* xd = (const float4*)(x + (size_t)d * N_NF);
#pragma unroll
    for (int k = 0; k < 4; k++) {
      float4 v = xs[k];
      A[4 * k + 0] = v.x; A[4 * k + 1] = v.y; A[4 * k + 2] = v.z; A[4 * k + 3] = v.w;
    }
#pragma unroll
    for (int k = 0; k < 4; k++) {
      float4 v = xd[k];
      A[16 + 4 * k + 0] = v.x; A[16 + 4 * k + 1] = v.y;
      A[16 + 4 * k + 2] = v.z; A[16 + 4 * k + 3] = v.w;
    }
    const float* er = e + (size_t)eidx * N_EF;
#pragma unroll
    for (int k = 0; k < N_EF; k++) A[2 * N_NF + k] = er[k];
  }

  layer<D0, D1, true>(sW1, sB1, A, B);
  layer<D1, D2, true>(sW2, sB2, B, A);
  layer<D2, D3, true>(sW3, sB3, A, B);
  layer<D3, D4, true>(sW4, sB4, B, A);
  layer<D4, D5, true>(sW5, sB5, A, B);
  layer<D5, D6, false>(sW6, sB6, B, A);

  ((float2*)out)[eidx] = make_float2(A[0], A[1]);
}

// ---------------- launch ----------------
extern "C" void kernel_launch(void* const* d_in, const int* in_sizes, int n_in,
                              void* d_out, int out_size, void* d_ws, size_t ws_size,
                              hipStream_t stream) {
  const float* x  = (const float*)d_in[0];
  const float* e  = (const float*)d_in[1];
  const int*   ei = (const int*)d_in[2];
  // d_in[3] = xbatch (unused)
  const float* ng = (const float*)d_in[4];
  const float* nb = (const float*)d_in[5];
  const float* eg = (const float*)d_in[6];
  const float* eb = (const float*)d_in[7];
  const float* W1 = (const float*)d_in[8];
  const float* b1 = (const float*)d_in[9];
  const float* W2 = (const float*)d_in[10];
  const float* b2 = (const float*)d_in[11];
  const float* W3 = (const float*)d_in[12];
  const float* b3 = (const float*)d_in[13];
  const float* W4 = (const float*)d_in[14];
  const float* b4 = (const float*)d_in[15];
  const float* W5 = (const float*)d_in[16];
  const float* b5 = (const float*)d_in[17];
  const float* W6 = (const float*)d_in[18];
  const float* b6 = (const float*)d_in[19];
  float* out = (float*)d_out;
  float* ws  = (float*)d_ws;

  // zero the stats accumulators (ws is poisoned 0xAA before every call)
  (void)hipMemsetAsync(ws, 0, 128 * sizeof(float), stream);

  col_stats_kernel<N_EF><<<1024, 256, 0, stream>>>(e, N_EDGES, ws + OFF_E_SUM, ws + OFF_E_SQ);
  col_stats_kernel<N_NF><<<128, 256, 0, stream>>>(x, N_NODES, ws + OFF_X_SUM, ws + OFF_X_SQ);
  fold_bn_kernel<<<1, 64, 0, stream>>>(ws, ng, nb, eg, eb, W1, b1,
                                       ws + OFF_W1P, ws + OFF_B1P);

  const int grid = (N_EDGES + 255) / 256;
  edge_mlp_kernel<<<grid, 256, 0, stream>>>(
      x, e, ei, ws + OFF_W1P, ws + OFF_B1P,
      W2, b2, W3, b3, W4, b4, W5, b5, W6, b6, out);
}

// Round 9
// 603.605 us; speedup vs baseline: 1.7665x; 1.7665x over previous
//
#include <hip/hip_runtime.h>

#define LEAK 0.1f
#define BN_EPS 1e-5f

constexpr int N_NODES = 100000;
constexpr int N_EDGES = 2000000;
constexpr int N_NF = 16;
constexpr int N_EF = 19;
constexpr int D0 = 2 * N_NF + N_EF;  // 51
constexpr int D1 = 64, D2 = 64, D3 = 32, D4 = 16, D5 = 8, D6 = 2;

// ws layout (in floats)
constexpr int OFF_E_SUM = 0;
constexpr int OFF_E_SQ  = 32;
constexpr int OFF_X_SUM = 64;
constexpr int OFF_X_SQ  = 96;
constexpr int OFF_W1P   = 256;                // 51*64 folded W1
constexpr int OFF_B1P   = OFF_W1P + D0 * D1;  // 64 folded b1

typedef __attribute__((ext_vector_type(8))) short short8;   // bf16x8 MFMA A/B frag
typedef __attribute__((ext_vector_type(4))) short short4v;  // 8B LDS write
typedef __attribute__((ext_vector_type(4))) float f32x4;    // MFMA C/D frag

// float -> bf16 bits, RNE (inputs finite; no NaN guard needed)
static __device__ __forceinline__ short f2bf(float f) {
  unsigned u = __builtin_bit_cast(unsigned, f);
  unsigned r = (u + 0x7FFFu + ((u >> 16) & 1u)) >> 16;
  return (short)r;
}

// ---------------- column stats (sum, sumsq) ----------------
template <int NF>
__global__ void col_stats_kernel(const float* __restrict__ v, int nrows,
                                 float* __restrict__ acc_sum,
                                 float* __restrict__ acc_sq) {
  float s[NF], qq[NF];
#pragma unroll
  for (int k = 0; k < NF; k++) { s[k] = 0.f; qq[k] = 0.f; }
  int tid = blockIdx.x * blockDim.x + threadIdx.x;
  int stride = gridDim.x * blockDim.x;
  for (int r = tid; r < nrows; r += stride) {
    const float* __restrict__ row = v + (size_t)r * NF;
#pragma unroll
    for (int k = 0; k < NF; k++) { float t = row[k]; s[k] += t; qq[k] += t * t; }
  }
#pragma unroll
  for (int k = 0; k < NF; k++) {
#pragma unroll
    for (int off = 32; off > 0; off >>= 1) {
      s[k] += __shfl_down(s[k], off);
      qq[k] += __shfl_down(qq[k], off);
    }
  }
  __shared__ float ls[4][2 * NF];
  int wave = threadIdx.x >> 6;
  int lane = threadIdx.x & 63;
  if (lane == 0) {
#pragma unroll
    for (int k = 0; k < NF; k++) { ls[wave][k] = s[k]; ls[wave][NF + k] = qq[k]; }
  }
  __syncthreads();
  if (threadIdx.x < 2 * NF) {
    float t = ls[0][threadIdx.x] + ls[1][threadIdx.x] + ls[2][threadIdx.x] +
              ls[3][threadIdx.x];
    if (threadIdx.x < NF) atomicAdd(&acc_sum[threadIdx.x], t);
    else                  atomicAdd(&acc_sq[threadIdx.x - NF], t);
  }
}

// ---------------- fold BN into W1/b1 ----------------
__global__ void fold_bn_kernel(const float* __restrict__ ws,
                               const float* __restrict__ ng, const float* __restrict__ nb,
                               const float* __restrict__ eg, const float* __restrict__ eb,
                               const float* __restrict__ W1, const float* __restrict__ b1,
                               float* __restrict__ W1p, float* __restrict__ b1p) {
  __shared__ float sc[D0], sh[D0];
  int t = threadIdx.x;  // 64 threads
  if (t < D0) {
    float mean, var, g, b;
    if (t < 2 * N_NF) {
      int k = t & (N_NF - 1);
      mean = ws[OFF_X_SUM + k] / (float)N_NODES;
      var  = ws[OFF_X_SQ + k] / (float)N_NODES - mean * mean;
      g = ng[k]; b = nb[k];
    } else {
      int k = t - 2 * N_NF;
      mean = ws[OFF_E_SUM + k] / (float)N_EDGES;
      var  = ws[OFF_E_SQ + k] / (float)N_EDGES - mean * mean;
      g = eg[k]; b = eb[k];
    }
    float scale = g / sqrtf(var + BN_EPS);
    sc[t] = scale;
    sh[t] = b - mean * scale;
  }
  __syncthreads();
  if (t < D1) {
    float accb = b1[t];
    for (int i = 0; i < D0; i++) {
      float w = W1[i * D1 + t];
      W1p[i * D1 + t] = w * sc[i];
      accb += sh[i] * w;
    }
    b1p[t] = accb;
  }
}

// ---------------- MFMA edge MLP ----------------
// Each wave owns a private LDS tile: 16 edge-rows x 64 bf16 cols (128B row stride),
// XOR-swizzled by ((row&7)<<4) to spread ds_read_b128 across banks.
// A-frag (16x16x32): lane l holds row m=l&15, k=(l>>4)*8+j  -> one b128/k-slice.
// B-frag: lane l holds col n=l&15, k=(l>>4)*8+j (weights, in registers).
// D: lane l holds col n=l&15, rows m=(l>>4)*4+r (r=0..3).

__device__ __forceinline__ short8 load_wfrag(const float* __restrict__ W, int ldn,
                                             int kbase, int nbase, int kmax, int nmax,
                                             int q, int g) {
  short8 f;
#pragma unroll
  for (int j = 0; j < 8; j++) {
    int k = kbase + g * 8 + j;
    int n = nbase + q;
    float w = (k < kmax && n < nmax) ? W[k * ldn + n] : 0.f;
    f[j] = f2bf(w);
  }
  return f;
}

template <int KT, int NT>
__device__ __forceinline__ void mfma_layer(char* lb, int q, int g, int swzq,
                                           const short8 (&wf)[KT][NT],
                                           const float (&bv)[NT]) {
  short8 a[KT];
#pragma unroll
  for (int kk = 0; kk < KT; kk++)
    a[kk] = *(const short8*)(lb + q * 128 + ((kk * 64 + g * 16) ^ swzq));
  f32x4 acc[NT];
#pragma unroll
  for (int nt = 0; nt < NT; nt++) {
    acc[nt] = (f32x4){bv[nt], bv[nt], bv[nt], bv[nt]};
#pragma unroll
    for (int kk = 0; kk < KT; kk++)
      acc[nt] = __builtin_amdgcn_mfma_f32_16x16x32_bf16(a[kk], wf[kk][nt], acc[nt], 0, 0, 0);
  }
  // lrelu + write back (bf16) to the same wave-private rows
#pragma unroll
  for (int nt = 0; nt < NT; nt++) {
#pragma unroll
    for (int r = 0; r < 4; r++) {
      float v = acc[nt][r];
      v = fmaxf(v, LEAK * v);
      int mw = 4 * g + r;
      *(short*)(lb + mw * 128 + ((nt * 32 + q * 2) ^ ((mw & 7) << 4))) = f2bf(v);
    }
  }
}

#define RED16(v)                 \
  v += __shfl_xor(v, 1);         \
  v += __shfl_xor(v, 2);         \
  v += __shfl_xor(v, 4);         \
  v += __shfl_xor(v, 8);

__global__ __launch_bounds__(256) void edge_mlp_mfma_kernel(
    const float* __restrict__ x, const float* __restrict__ e,
    const int* __restrict__ ei,
    const float* __restrict__ W1p, const float* __restrict__ b1p,
    const float* __restrict__ W2, const float* __restrict__ b2,
    const float* __restrict__ W3, const float* __restrict__ b3,
    const float* __restrict__ W4, const float* __restrict__ b4,
    const float* __restrict__ W5, const float* __restrict__ b5,
    const float* __restrict__ W6, const float* __restrict__ b6,
    float* __restrict__ out) {
  __shared__ __align__(16) char actbuf[4 * 16 * 128];  // 4 waves x 16 rows x 128B

  const int lane = threadIdx.x & 63;
  const int wave = threadIdx.x >> 6;
  const int q = lane & 15;        // edge-row (stage/read) / out-col n (B,D)
  const int g = lane >> 4;        // k-group / m-group
  const int swzq = (q & 7) << 4;
  char* lb = actbuf + wave * 2048;

  // ---- weights -> per-lane register fragments (once per block) ----
  short8 w1f[2][4], w2f[2][4], w3f[2][2], w4f[1][1];
  float b1v[4], b2v[4], b3v[2], b4v[1];
#pragma unroll
  for (int kk = 0; kk < 2; kk++)
#pragma unroll
    for (int nt = 0; nt < 4; nt++) {
      w1f[kk][nt] = load_wfrag(W1p, 64, kk * 32, nt * 16, D0, 64, q, g);
      w2f[kk][nt] = load_wfrag(W2, 64, kk * 32, nt * 16, 64, 64, q, g);
    }
#pragma unroll
  for (int kk = 0; kk < 2; kk++)
#pragma unroll
    for (int nt = 0; nt < 2; nt++)
      w3f[kk][nt] = load_wfrag(W3, 32, kk * 32, nt * 16, 64, 32, q, g);
  w4f[0][0] = load_wfrag(W4, 16, 0, 0, 32, 16, q, g);
  short8 w5f = load_wfrag(W5, 8, 0, 0, 16, 8, q, g);
#pragma unroll
  for (int nt = 0; nt < 4; nt++) { b1v[nt] = b1p[nt * 16 + q]; b2v[nt] = b2[nt * 16 + q]; }
#pragma unroll
  for (int nt = 0; nt < 2; nt++) b3v[nt] = b3[nt * 16 + q];
  b4v[0] = b4[q];
  float b5v = (q < 8) ? b5[q] : 0.f;
  float w60 = (q < 8) ? W6[q * 2 + 0] : 0.f;
  float w61 = (q < 8) ? W6[q * 2 + 1] : 0.f;
  float b60 = b6[0], b61 = b6[1];

  const int n_bt = N_EDGES / 64;  // 31250 block-tiles of 64 edges
  for (int bt = blockIdx.x; bt < n_bt; bt += gridDim.x) {
    const int Eb = bt * 64 + wave * 16;  // this wave's 16 edges
    const int eidx = Eb + q;

    // ---- stage: A row q = [x[src](16) | x[dst](16) | e(19) | zeros] as bf16 ----
    const int src = ei[eidx];
    const int dst = ei[N_EDGES + eidx];
    {
      float4 vs = ((const float4*)x)[(size_t)src * 4 + g];
      short4v ps = {f2bf(vs.x), f2bf(vs.y), f2bf(vs.z), f2bf(vs.w)};
      *(short4v*)(lb + q * 128 + ((g * 8) ^ swzq)) = ps;
      float4 vd = ((const float4*)x)[(size_t)dst * 4 + g];
      short4v pd = {f2bf(vd.x), f2bf(vd.y), f2bf(vd.z), f2bf(vd.w)};
      *(short4v*)(lb + q * 128 + ((32 + g * 8) ^ swzq)) = pd;
      const float* er = e + (size_t)eidx * N_EF;
      float e0 = er[g * 4 + 0], e1 = er[g * 4 + 1], e2 = er[g * 4 + 2], e3 = er[g * 4 + 3];
      short4v pe = {f2bf(e0), f2bf(e1), f2bf(e2), f2bf(e3)};
      *(short4v*)(lb + q * 128 + ((64 + g * 8) ^ swzq)) = pe;
      // cols 48-63: explicit init (NaN fix: uninitialized LDS bf16 can be
      // NaN and NaN*0=NaN in the MFMA K-reduction). g=0 writes the e tail
      // {e16,e17,e18,0}; g=1..3 write zeros -> bytes 96..127 all defined.
      short4v pt;
      if (g == 0) pt = (short4v){f2bf(er[16]), f2bf(er[17]), f2bf(er[18]), 0};
      else        pt = (short4v){0, 0, 0, 0};
      *(short4v*)(lb + q * 128 + ((96 + g * 8) ^ swzq)) = pt;
    }

    // ---- layers 1-4 (MFMA, LDS round-trip) ----
    mfma_layer<2, 4>(lb, q, g, swzq, w1f, b1v);
    mfma_layer<2, 4>(lb, q, g, swzq, w2f, b2v);
    mfma_layer<2, 2>(lb, q, g, swzq, w3f, b3v);
    mfma_layer<1, 1>(lb, q, g, swzq, w4f, b4v);

    // ---- layer 5 (MFMA, keep in regs) ----
    short8 a5 = *(const short8*)(lb + q * 128 + ((g * 16) ^ swzq));
    f32x4 acc5 = (f32x4){b5v, b5v, b5v, b5v};
    acc5 = __builtin_amdgcn_mfma_f32_16x16x32_bf16(a5, w5f, acc5, 0, 0, 0);
    float a50 = fmaxf(acc5[0], LEAK * acc5[0]);
    float a51 = fmaxf(acc5[1], LEAK * acc5[1]);
    float a52 = fmaxf(acc5[2], LEAK * acc5[2]);
    float a53 = fmaxf(acc5[3], LEAK * acc5[3]);

    // ---- layer 6 (VALU + 16-lane reduce): out[m][o] = sum_n a5[m][n]*W6[n][o]+b6 ----
    float s00 = a50 * w60, s10 = a50 * w61;
    float s01 = a51 * w60, s11 = a51 * w61;
    float s02 = a52 * w60, s12 = a52 * w61;
    float s03 = a53 * w60, s13 = a53 * w61;
    RED16(s00) RED16(s10) RED16(s01) RED16(s11)
    RED16(s02) RED16(s12) RED16(s03) RED16(s13)
    if (q < 4) {
      float o0 = (q == 0) ? s00 : (q == 1) ? s01 : (q == 2) ? s02 : s03;
      float o1 = (q == 0) ? s10 : (q == 1) ? s11 : (q == 2) ? s12 : s13;
      ((float2*)out)[(size_t)Eb + g * 4 + q] = make_float2(o0 + b60, o1 + b61);
    }
  }
}

// ---------------- launch ----------------
extern "C" void kernel_launch(void* const* d_in, const int* in_sizes, int n_in,
                              void* d_out, int out_size, void* d_ws, size_t ws_size,
                              hipStream_t stream) {
  const float* x  = (const float*)d_in[0];
  const float* e  = (const float*)d_in[1];
  const int*   ei = (const int*)d_in[2];
  const float* ng = (const float*)d_in[4];
  const float* nb = (const float*)d_in[5];
  const float* eg = (const float*)d_in[6];
  const float* eb = (const float*)d_in[7];
  const float* W1 = (const float*)d_in[8];
  const float* b1 = (const float*)d_in[9];
  const float* W2 = (const float*)d_in[10];
  const float* b2 = (const float*)d_in[11];
  const float* W3 = (const float*)d_in[12];
  const float* b3 = (const float*)d_in[13];
  const float* W4 = (const float*)d_in[14];
  const float* b4 = (const float*)d_in[15];
  const float* W5 = (const float*)d_in[16];
  const float* b5 = (const float*)d_in[17];
  const float* W6 = (const float*)d_in[18];
  const float* b6 = (const float*)d_in[19];
  float* out = (float*)d_out;
  float* ws  = (float*)d_ws;

  (void)hipMemsetAsync(ws, 0, 128 * sizeof(float), stream);

  col_stats_kernel<N_EF><<<1024, 256, 0, stream>>>(e, N_EDGES, ws + OFF_E_SUM, ws + OFF_E_SQ);
  col_stats_kernel<N_NF><<<128, 256, 0, stream>>>(x, N_NODES, ws + OFF_X_SUM, ws + OFF_X_SQ);
  fold_bn_kernel<<<1, 64, 0, stream>>>(ws, ng, nb, eg, eb, W1, b1,
                                       ws + OFF_W1P, ws + OFF_B1P);

  edge_mlp_mfma_kernel<<<2048, 256, 0, stream>>>(
      x, e, ei, ws + OFF_W1P, ws + OFF_B1P,
      W2, b2, W3, b3, W4, b4, W5, b5, W6, b6, out);
}

// Round 12
// 531.380 us; speedup vs baseline: 2.0066x; 1.1359x over previous
//
#include <hip/hip_runtime.h>

#define LEAK 0.1f
#define BN_EPS 1e-5f

constexpr int N_NODES = 100000;
constexpr int N_EDGES = 2000000;
constexpr int N_NF = 16;
constexpr int N_EF = 19;
constexpr int D0 = 2 * N_NF + N_EF;  // 51
constexpr int D1 = 64, D2 = 64, D3 = 32, D4 = 16, D5 = 8, D6 = 2;

// ws layout (in floats)
constexpr int OFF_E_SUM = 0;
constexpr int OFF_E_SQ  = 32;
constexpr int OFF_X_SUM = 64;
constexpr int OFF_X_SQ  = 96;
constexpr int OFF_W1P   = 256;                // 51*64 folded W1
constexpr int OFF_B1P   = OFF_W1P + D0 * D1;  // 64 folded b1

typedef __attribute__((ext_vector_type(8))) short short8;   // bf16x8 MFMA A/B frag
typedef __attribute__((ext_vector_type(4))) short short4v;  // 8B LDS write
typedef __attribute__((ext_vector_type(4))) float f32x4;    // MFMA C/D frag

// float -> bf16 bits, RNE (inputs finite)
static __device__ __forceinline__ short f2bf(float f) {
  unsigned u = __builtin_bit_cast(unsigned, f);
  unsigned r = (u + 0x7FFFu + ((u >> 16) & 1u)) >> 16;
  return (short)r;
}

// ---------------- e column stats: LDS-staged, coalesced ----------------
// Chunk = 256 rows x 19 floats = 19456B (1216 float4, 16B-aligned since
// 19456 % 16 == 0). Coalesced float4 global loads -> LDS; 247 threads
// accumulate column t%19, row-stride 13. Tail chunk = 128 rows (608 float4).
constexpr int SROWS = 256;
__global__ __launch_bounds__(256) void e_stats_kernel(const float* __restrict__ v,
                                                      float* __restrict__ acc_sum,
                                                      float* __restrict__ acc_sq) {
  __shared__ float lbuf[SROWS * N_EF];  // 4864 floats
  const int t = threadIdx.x;
  float s = 0.f, qq = 0.f;
  const int col = t % N_EF;
  const int rep = t / N_EF;  // rep<13 for t<247
  const int nchunks = (N_EDGES + SROWS - 1) / SROWS;
  for (int c = blockIdx.x; c < nchunks; c += gridDim.x) {
    const int nr = min(SROWS, N_EDGES - c * SROWS);
    const int nf4 = nr * N_EF / 4;  // nr is 256 or 128 -> divisible
    const float4* src = (const float4*)(v + (size_t)c * SROWS * N_EF);
    for (int i = t; i < nf4; i += 256) ((float4*)lbuf)[i] = src[i];
    __syncthreads();
    if (rep < 13) {
      for (int r = rep; r < nr; r += 13) {
        float x = lbuf[r * N_EF + col];
        s += x; qq += x * x;
      }
    }
    __syncthreads();
  }
  lbuf[t] = s; lbuf[256 + t] = qq;
  __syncthreads();
  if (t < N_EF) {
    float ts = 0.f, tq = 0.f;
#pragma unroll
    for (int rp = 0; rp < 13; rp++) {
      ts += lbuf[t + N_EF * rp];
      tq += lbuf[256 + t + N_EF * rp];
    }
    atomicAdd(&acc_sum[t], ts);
    atomicAdd(&acc_sq[t], tq);
  }
}

// ---------------- x column stats (6.4MB, cheap) ----------------
template <int NF>
__global__ void col_stats_kernel(const float* __restrict__ v, int nrows,
                                 float* __restrict__ acc_sum,
                                 float* __restrict__ acc_sq) {
  float s[NF], qq[NF];
#pragma unroll
  for (int k = 0; k < NF; k++) { s[k] = 0.f; qq[k] = 0.f; }
  int tid = blockIdx.x * blockDim.x + threadIdx.x;
  int stride = gridDim.x * blockDim.x;
  for (int r = tid; r < nrows; r += stride) {
    const float* __restrict__ row = v + (size_t)r * NF;
#pragma unroll
    for (int k = 0; k < NF; k++) { float t = row[k]; s[k] += t; qq[k] += t * t; }
  }
#pragma unroll
  for (int k = 0; k < NF; k++) {
#pragma unroll
    for (int off = 32; off > 0; off >>= 1) {
      s[k] += __shfl_down(s[k], off);
      qq[k] += __shfl_down(qq[k], off);
    }
  }
  __shared__ float ls[4][2 * NF];
  int wave = threadIdx.x >> 6;
  int lane = threadIdx.x & 63;
  if (lane == 0) {
#pragma unroll
    for (int k = 0; k < NF; k++) { ls[wave][k] = s[k]; ls[wave][NF + k] = qq[k]; }
  }
  __syncthreads();
  if (threadIdx.x < 2 * NF) {
    float t = ls[0][threadIdx.x] + ls[1][threadIdx.x] + ls[2][threadIdx.x] +
              ls[3][threadIdx.x];
    if (threadIdx.x < NF) atomicAdd(&acc_sum[threadIdx.x], t);
    else                  atomicAdd(&acc_sq[threadIdx.x - NF], t);
  }
}

// ---------------- fold BN into W1/b1 ----------------
__global__ void fold_bn_kernel(const float* __restrict__ ws,
                               const float* __restrict__ ng, const float* __restrict__ nb,
                               const float* __restrict__ eg, const float* __restrict__ eb,
                               const float* __restrict__ W1, const float* __restrict__ b1,
                               float* __restrict__ W1p, float* __restrict__ b1p) {
  __shared__ float sc[D0], sh[D0];
  int t = threadIdx.x;  // 64 threads
  if (t < D0) {
    float mean, var, g, b;
    if (t < 2 * N_NF) {
      int k = t & (N_NF - 1);
      mean = ws[OFF_X_SUM + k] / (float)N_NODES;
      var  = ws[OFF_X_SQ + k] / (float)N_NODES - mean * mean;
      g = ng[k]; b = nb[k];
    } else {
      int k = t - 2 * N_NF;
      mean = ws[OFF_E_SUM + k] / (float)N_EDGES;
      var  = ws[OFF_E_SQ + k] / (float)N_EDGES - mean * mean;
      g = eg[k]; b = eb[k];
    }
    float scale = g / sqrtf(var + BN_EPS);
    sc[t] = scale;
    sh[t] = b - mean * scale;
  }
  __syncthreads();
  if (t < D1) {
    float accb = b1[t];
    for (int i = 0; i < D0; i++) {
      float w = W1[i * D1 + t];
      W1p[i * D1 + t] = w * sc[i];
      accb += sh[i] * w;
    }
    b1p[t] = accb;
  }
}

// ---------------- MFMA edge MLP (M=32/wave, dbuf + prefetch) ----------------
// Wave-private LDS tile: 32 edge-rows x 64 bf16 cols (128B stride), XOR swizzle
// ((row&7)<<4). Two independent 16-row MFMA chains share W frags (2x ILP).
// A-frag: lane holds row m=l&15 (+roff), k=(l>>4)*8+j. B: lane=col n, same k.
// D: lane=col n=l&15, rows m=(l>>4)*4+r.

__device__ __forceinline__ short8 load_wfrag(const float* __restrict__ W, int ldn,
                                             int kbase, int nbase, int kmax, int nmax,
                                             int q, int g) {
  short8 f;
#pragma unroll
  for (int j = 0; j < 8; j++) {
    int k = kbase + g * 8 + j;
    int n = nbase + q;
    float w = (k < kmax && n < nmax) ? W[k * ldn + n] : 0.f;
    f[j] = f2bf(w);
  }
  return f;
}

struct Pref {
  float4 vs, vd;
  float e0, e1, e2, e3;
  float t0, t1, t2;
};

__device__ __forceinline__ Pref load_gather(int eidx, int g,
                                            const float* __restrict__ x,
                                            const float* __restrict__ e,
                                            const int* __restrict__ ei) {
  Pref p;
  const int src = ei[eidx];
  const int dst = ei[N_EDGES + eidx];
  p.vs = ((const float4*)x)[(size_t)src * 4 + g];
  p.vd = ((const float4*)x)[(size_t)dst * 4 + g];
  const float* er = e + (size_t)eidx * N_EF;
  p.e0 = er[g * 4 + 0]; p.e1 = er[g * 4 + 1];
  p.e2 = er[g * 4 + 2]; p.e3 = er[g * 4 + 3];
  if (g == 0) { p.t0 = er[16]; p.t1 = er[17]; p.t2 = er[18]; }
  else        { p.t0 = 0.f; p.t1 = 0.f; p.t2 = 0.f; }
  return p;
}

__device__ __forceinline__ void stage_row(char* lb, int row, int swzq, int g,
                                          const Pref& p) {
  char* base = lb + row * 128;
  short4v ps = {f2bf(p.vs.x), f2bf(p.vs.y), f2bf(p.vs.z), f2bf(p.vs.w)};
  *(short4v*)(base + ((g * 8) ^ swzq)) = ps;
  short4v pd = {f2bf(p.vd.x), f2bf(p.vd.y), f2bf(p.vd.z), f2bf(p.vd.w)};
  *(short4v*)(base + ((32 + g * 8) ^ swzq)) = pd;
  short4v pe = {f2bf(p.e0), f2bf(p.e1), f2bf(p.e2), f2bf(p.e3)};
  *(short4v*)(base + ((64 + g * 8) ^ swzq)) = pe;
  short4v pt = {f2bf(p.t0), f2bf(p.t1), f2bf(p.t2), 0};  // all bytes defined
  *(short4v*)(base + ((96 + g * 8) ^ swzq)) = pt;
}

template <int KT, int NT>
__device__ __forceinline__ void mfma_layer2(char* lb, int q, int g, int swzq,
                                            const short8 (&wf)[KT][NT],
                                            const float (&bv)[NT]) {
  short8 a0[KT], a1[KT];
#pragma unroll
  for (int kk = 0; kk < KT; kk++) {
    a0[kk] = *(const short8*)(lb + q * 128 + ((kk * 64 + g * 16) ^ swzq));
    a1[kk] = *(const short8*)(lb + (q + 16) * 128 + ((kk * 64 + g * 16) ^ swzq));
  }
  f32x4 acc0[NT], acc1[NT];
#pragma unroll
  for (int nt = 0; nt < NT; nt++) {
    acc0[nt] = (f32x4){bv[nt], bv[nt], bv[nt], bv[nt]};
    acc1[nt] = acc0[nt];
#pragma unroll
    for (int kk = 0; kk < KT; kk++) {
      acc0[nt] = __builtin_amdgcn_mfma_f32_16x16x32_bf16(a0[kk], wf[kk][nt], acc0[nt], 0, 0, 0);
      acc1[nt] = __builtin_amdgcn_mfma_f32_16x16x32_bf16(a1[kk], wf[kk][nt], acc1[nt], 0, 0, 0);
    }
  }
#pragma unroll
  for (int nt = 0; nt < NT; nt++) {
#pragma unroll
    for (int r = 0; r < 4; r++) {
      float v0 = acc0[nt][r];
      v0 = fmaxf(v0, LEAK * v0);
      int mw0 = 4 * g + r;
      *(short*)(lb + mw0 * 128 + ((nt * 32 + q * 2) ^ ((mw0 & 7) << 4))) = f2bf(v0);
      float v1 = acc1[nt][r];
      v1 = fmaxf(v1, LEAK * v1);
      int mw1 = 16 + 4 * g + r;
      *(short*)(lb + mw1 * 128 + ((nt * 32 + q * 2) ^ ((mw1 & 7) << 4))) = f2bf(v1);
    }
  }
}

#define RED16(v)                 \
  v += __shfl_xor(v, 1);         \
  v += __shfl_xor(v, 2);         \
  v += __shfl_xor(v, 4);         \
  v += __shfl_xor(v, 8);

__device__ __forceinline__ void tail56(char* lb, int roff, int q, int g, int swzq,
                                       short8 w5f, float b5v, float w60, float w61,
                                       float b60, float b61, float* out, int Eb) {
  short8 a5 = *(const short8*)(lb + (q + roff) * 128 + ((g * 16) ^ swzq));
  f32x4 acc5 = (f32x4){b5v, b5v, b5v, b5v};
  acc5 = __builtin_amdgcn_mfma_f32_16x16x32_bf16(a5, w5f, acc5, 0, 0, 0);
  float a50 = fmaxf(acc5[0], LEAK * acc5[0]);
  float a51 = fmaxf(acc5[1], LEAK * acc5[1]);
  float a52 = fmaxf(acc5[2], LEAK * acc5[2]);
  float a53 = fmaxf(acc5[3], LEAK * acc5[3]);
  float s00 = a50 * w60, s10 = a50 * w61;
  float s01 = a51 * w60, s11 = a51 * w61;
  float s02 = a52 * w60, s12 = a52 * w61;
  float s03 = a53 * w60, s13 = a53 * w61;
  RED16(s00) RED16(s10) RED16(s01) RED16(s11)
  RED16(s02) RED16(s12) RED16(s03) RED16(s13)
  if (q < 4) {
    float o0 = (q == 0) ? s00 : (q == 1) ? s01 : (q == 2) ? s02 : s03;
    float o1 = (q == 0) ? s10 : (q == 1) ? s11 : (q == 2) ? s12 : s13;
    ((float2*)out)[(size_t)Eb + roff + g * 4 + q] = make_float2(o0 + b60, o1 + b61);
  }
}

__global__ __launch_bounds__(256, 2) void edge_mlp_mfma_kernel(
    const float* __restrict__ x, const float* __restrict__ e,
    const int* __restrict__ ei,
    const float* __restrict__ W1p, const float* __restrict__ b1p,
    const float* __restrict__ W2, const float* __restrict__ b2,
    const float* __restrict__ W3, const float* __restrict__ b3,
    const float* __restrict__ W4, const float* __restrict__ b4,
    const float* __restrict__ W5, const float* __restrict__ b5,
    const float* __restrict__ W6, const float* __restrict__ b6,
    float* __restrict__ out) {
  __shared__ __align__(16) char actbuf[4 * 2 * 32 * 128];  // 4 waves x 2 bufs x 4KB

  const int lane = threadIdx.x & 63;
  const int wave = threadIdx.x >> 6;
  const int q = lane & 15;
  const int g = lane >> 4;
  const int swzq = (q & 7) << 4;

  // ---- weights -> per-lane register fragments (once per block) ----
  short8 w1f[2][4], w2f[2][4], w3f[2][2], w4f[1][1];
  float b1v[4], b2v[4], b3v[2], b4v[1];
#pragma unroll
  for (int kk = 0; kk < 2; kk++)
#pragma unroll
    for (int nt = 0; nt < 4; nt++) {
      w1f[kk][nt] = load_wfrag(W1p, 64, kk * 32, nt * 16, D0, 64, q, g);
      w2f[kk][nt] = load_wfrag(W2, 64, kk * 32, nt * 16, 64, 64, q, g);
    }
#pragma unroll
  for (int kk = 0; kk < 2; kk++)
#pragma unroll
    for (int nt = 0; nt < 2; nt++)
      w3f[kk][nt] = load_wfrag(W3, 32, kk * 32, nt * 16, 64, 32, q, g);
  w4f[0][0] = load_wfrag(W4, 16, 0, 0, 32, 16, q, g);
  short8 w5f = load_wfrag(W5, 8, 0, 0, 16, 8, q, g);
#pragma unroll
  for (int nt = 0; nt < 4; nt++) { b1v[nt] = b1p[nt * 16 + q]; b2v[nt] = b2[nt * 16 + q]; }
#pragma unroll
  for (int nt = 0; nt < 2; nt++) b3v[nt] = b3[nt * 16 + q];
  b4v[0] = b4[q];
  float b5v = (q < 8) ? b5[q] : 0.f;
  float w60 = (q < 8) ? W6[q * 2 + 0] : 0.f;
  float w61 = (q < 8) ? W6[q * 2 + 1] : 0.f;
  float b60 = b6[0], b61 = b6[1];

  const int n_bt = N_EDGES / 128;  // 15625 block-tiles of 128 edges
  int buf = 0;
  int bt0 = blockIdx.x;
  Pref c1, c2;
  if (bt0 < n_bt) {
    const int Eb0 = bt0 * 128 + wave * 32;
    c1 = load_gather(Eb0 + q, g, x, e, ei);
    c2 = load_gather(Eb0 + 16 + q, g, x, e, ei);
  }
  for (int bt = bt0; bt < n_bt; bt += gridDim.x) {
    const int Eb = bt * 128 + wave * 32;
    // ---- prefetch next tile's gathers (T14: issue early, consume next iter)
    const int nbt = bt + gridDim.x;
    Pref n1 = c1, n2 = c2;
    if (nbt < n_bt) {
      const int nEb = nbt * 128 + wave * 32;
      n1 = load_gather(nEb + q, g, x, e, ei);
      n2 = load_gather(nEb + 16 + q, g, x, e, ei);
    }
    char* lb = actbuf + wave * 8192 + buf * 4096;
    // ---- stage rows q and q+16 ----
    stage_row(lb, q, swzq, g, c1);
    stage_row(lb, q + 16, swzq, g, c2);
    // ---- layers 1-4 (two 16-row chains interleaved) ----
    mfma_layer2<2, 4>(lb, q, g, swzq, w1f, b1v);
    mfma_layer2<2, 4>(lb, q, g, swzq, w2f, b2v);
    mfma_layer2<2, 2>(lb, q, g, swzq, w3f, b3v);
    mfma_layer2<1, 1>(lb, q, g, swzq, w4f, b4v);
    // ---- layers 5+6 per sub-tile ----
    tail56(lb, 0,  q, g, swzq, w5f, b5v, w60, w61, b60, b61, out, Eb);
    tail56(lb, 16, q, g, swzq, w5f, b5v, w60, w61, b60, b61, out, Eb);
    c1 = n1; c2 = n2; buf ^= 1;
  }
}

// ---------------- launch ----------------
extern "C" void kernel_launch(void* const* d_in, const int* in_sizes, int n_in,
                              void* d_out, int out_size, void* d_ws, size_t ws_size,
                              hipStream_t stream) {
  const float* x  = (const float*)d_in[0];
  const float* e  = (const float*)d_in[1];
  const int*   ei = (const int*)d_in[2];
  const float* ng = (const float*)d_in[4];
  const float* nb = (const float*)d_in[5];
  const float* eg = (const float*)d_in[6];
  const float* eb = (const float*)d_in[7];
  const float* W1 = (const float*)d_in[8];
  const float* b1 = (const float*)d_in[9];
  const float* W2 = (const float*)d_in[10];
  const float* b2 = (const float*)d_in[11];
  const float* W3 = (const float*)d_in[12];
  const float* b3 = (const float*)d_in[13];
  const float* W4 = (const float*)d_in[14];
  const float* b4 = (const float*)d_in[15];
  const float* W5 = (const float*)d_in[16];
  const float* b5 = (const float*)d_in[17];
  const float* W6 = (const float*)d_in[18];
  const float* b6 = (const float*)d_in[19];
  float* out = (float*)d_out;
  float* ws  = (float*)d_ws;

  (void)hipMemsetAsync(ws, 0, 128 * sizeof(float), stream);

  e_stats_kernel<<<1024, 256, 0, stream>>>(e, ws + OFF_E_SUM, ws + OFF_E_SQ);
  col_stats_kernel<N_NF><<<128, 256, 0, stream>>>(x, N_NODES, ws + OFF_X_SUM, ws + OFF_X_SQ);
  fold_bn_kernel<<<1, 64, 0, stream>>>(ws, ng, nb, eg, eb, W1, b1,
                                       ws + OFF_W1P, ws + OFF_B1P);

  edge_mlp_mfma_kernel<<<2048, 256, 0, stream>>>(
      x, e, ei, ws + OFF_W1P, ws + OFF_B1P,
      W2, b2, W3, b3, W4, b4, W5, b5, W6, b6, out);
}